// Round 2
// baseline (1259.464 us; speedup 1.0000x reference)
//
#include <hip/hip_runtime.h>

typedef __attribute__((ext_vector_type(8))) unsigned short us8;
typedef __attribute__((ext_vector_type(8))) __bf16 bf16x8;
typedef __attribute__((ext_vector_type(4))) float f32x4;

#define DP  26      // padded plane dim
#define CIP 40      // padded K-slot stride in LDS (shorts); 80B rows -> stride-5 16B slots, conflict-free
#define WELEMS 165888   // 3*64*32*27 weight elements (one bf16 plane)

// Reference semantics (derived from xp.reshape(B*D0p, Ci, ...) WITHOUT transpose):
//   out[b,o,d0,d1,d2,d3] = bias[o] + sum_{i<3, c<32, k1,k2,k3}
//       X(b, r=(d0+i)*32+c ; d1+k1-1, d2+k2-1, d3+k3-1) * w[i,o,c,k1,k2,k3]
//   where X(b, r; ...) reads x[b, ci=r/26, pf=r%26-1, ...], zero if pf not in [0,24)
//   or any spatial index out of [0,24).
//
// fp32-exactness: split-bf16 3-term MFMA (x=hi+lo, w=hi+lo; acc += Ahh+Ahl+Alh).
//
// Round-2 change: staging rewritten wave-per-K-slot. Old scheme issued 8 scalar
// ds_write_u16 per float4 at banks (8*d2+16*d3c) mod 32 => ~8-way conflicts,
// 1.25e8 conflict cycles (~204us/CU). New scheme: wave wv stages c=wv*8..wv*8+7;
// each lane handles one (d2,d3): 8 branchless global loads (wave-uniform per-c
// offsets hoisted out of the loop), 2x ds_write_b128 at the same conflict-free
// 80B stride the MFMA fragment reads use.

__device__ __forceinline__ unsigned short f2bf(float f) {
    unsigned int u = __builtin_bit_cast(unsigned int, f);
    u += 0x7FFFu + ((u >> 16) & 1u);
    return (unsigned short)(u >> 16);
}

__device__ __forceinline__ void f2bf2(float f, unsigned short& h, unsigned short& l) {
    h = f2bf(f);
    float hf = __builtin_bit_cast(float, (unsigned int)h << 16);
    l = f2bf(f - hf);   // exact fp32 subtract (hi within 2x of f), then round
}

// w: (3,64,32,3,3,3) fp32  ->  w2 bf16 [i][k1][k2][k3][o][c], hi plane + lo plane
__global__ void wconv_kernel(const float* __restrict__ w, unsigned short* __restrict__ w2) {
    int e   = blockIdx.x * 256 + threadIdx.x;   // 648*256 = 165888 exact
    int ci  = e & 31;
    int o   = (e >> 5) & 63;
    int tap = e >> 11;
    int k3 = tap % 3;
    int k2 = (tap / 3) % 3;
    int k1 = (tap / 9) % 3;
    int i  = tap / 27;
    int src = ((i * 64 + o) * 32 + ci) * 27 + (k1 * 9 + k2 * 3 + k3);
    unsigned short h, l;
    f2bf2(w[src], h, l);
    w2[e]          = h;
    w2[e + WELEMS] = l;
}

__global__ __launch_bounds__(256, 1)
void conv4d_kernel(const float* __restrict__ x, const unsigned short* __restrict__ w2,
                   const float* __restrict__ bias, float* __restrict__ out) {
    __shared__ __align__(16) unsigned short xsh[DP * DP * CIP];  // 54,080 B (hi)
    __shared__ __align__(16) unsigned short xsl[DP * DP * CIP];  // 54,080 B (lo)
    __shared__ __align__(16) float tb[4][320];                   //  5,120 B

    const int tid  = threadIdx.x;
    const int lane = tid & 63;
    const int wv   = tid >> 6;
    const int n    = lane & 15;
    const int q    = lane >> 4;

    const int bid = blockIdx.x;
    const int d1 = bid % 24;
    const int d0 = (bid / 24) % 24;
    const int b  = bid / 576;

    for (int e = tid; e < DP * DP * CIP; e += 256) { xsh[e] = 0; xsl[e] = 0; }

    int abase[9];
    #pragma unroll
    for (int t = 0; t < 9; ++t) {
        int mflat = (wv * 9 + t) * 16 + n;
        int d2o = mflat / 24;
        int d3o = mflat - d2o * 24;
        abase[t] = (d2o * DP + d3o) * CIP + q * 8;
    }

    f32x4 acc[9][4];
    #pragma unroll
    for (int t = 0; t < 9; ++t)
        #pragma unroll
        for (int nt = 0; nt < 4; ++nt)
            acc[t][nt] = (f32x4)0.0f;

    const float* xb_b = x + (size_t)b * 10616832;

    for (int i = 0; i < 3; ++i) {                 // NO d0-skip: f=d0+i always valid
        const int rbase = (d0 + i) * 32;
        for (int k1 = 0; k1 < 3; ++k1) {
            int d1in = d1 + k1 - 1;
            if (d1in < 0 || d1in >= 24) continue; // spatial pad, block-uniform

            __syncthreads();
            {
                // per-stage, wave-uniform per-c source offsets (+ validity mask)
                int   off8[8];
                float msk8[8];
                #pragma unroll
                for (int cc = 0; cc < 8; ++cc) {
                    int r  = rbase + wv * 8 + cc;
                    int ci = r / 26;
                    int pf = r - ci * 26 - 1;       // source frame, may be pad
                    bool valid = (pf >= 0 && pf < 24);
                    off8[cc] = valid ? (ci * 331776 + pf * 13824 + d1in * 576) : 0;
                    msk8[cc] = valid ? 1.0f : 0.0f;
                }
                const int cbase = wv * 8;
                #pragma unroll
                for (int j = 0; j < 9; ++j) {
                    int pos = lane + 64 * j;        // 0..575 = d2*24 + d3
                    int d2  = pos / 24;
                    int d3  = pos - d2 * 24;
                    us8 hv, lv;
                    #pragma unroll
                    for (int cc = 0; cc < 8; ++cc) {
                        float v = xb_b[off8[cc] + pos] * msk8[cc];  // branchless; *0 kills pad reads
                        unsigned short h, l;
                        f2bf2(v, h, l);
                        hv[cc] = h; lv[cc] = l;
                    }
                    int le = ((d2 + 1) * DP + (d3 + 1)) * CIP + cbase;  // 16B aligned (80B rows)
                    *(us8*)&xsh[le] = hv;
                    *(us8*)&xsl[le] = lv;
                }
            }
            __syncthreads();

            const unsigned short* wsliceH = w2 + (size_t)((i * 3 + k1) * 9) * 2048;
            const unsigned short* wsliceL = wsliceH + WELEMS;
            #pragma unroll
            for (int k2 = 0; k2 < 3; ++k2) {
                #pragma unroll
                for (int k3 = 0; k3 < 3; ++k3) {
                    const int tap = k2 * 3 + k3;
                    bf16x8 bh[4], bl[4];
                    #pragma unroll
                    for (int nt = 0; nt < 4; ++nt) {
                        const int wo = (tap * 64 + nt * 16 + n) * 32 + q * 8;
                        bh[nt] = __builtin_bit_cast(bf16x8, *(const us8*)(wsliceH + wo));
                        bl[nt] = __builtin_bit_cast(bf16x8, *(const us8*)(wsliceL + wo));
                    }
                    const int toff = (k2 * DP + k3) * CIP;
                    #pragma unroll
                    for (int t = 0; t < 9; ++t) {
                        const bf16x8 ah = __builtin_bit_cast(bf16x8, *(const us8*)(&xsh[abase[t] + toff]));
                        const bf16x8 al = __builtin_bit_cast(bf16x8, *(const us8*)(&xsl[abase[t] + toff]));
                        #pragma unroll
                        for (int nt = 0; nt < 4; ++nt) {
                            acc[t][nt] = __builtin_amdgcn_mfma_f32_16x16x32_bf16(ah, bh[nt], acc[t][nt], 0, 0, 0);
                            acc[t][nt] = __builtin_amdgcn_mfma_f32_16x16x32_bf16(ah, bl[nt], acc[t][nt], 0, 0, 0);
                            acc[t][nt] = __builtin_amdgcn_mfma_f32_16x16x32_bf16(al, bh[nt], acc[t][nt], 0, 0, 0);
                        }
                    }
                }
            }
        }
    }

    // epilogue, interp A (col=o, row=m — certified by round-2 on-device probes)
    const int o4 = lane >> 2;
    const int mc = lane & 3;
    float* tbw = tb[wv];
    const size_t plane = (size_t)d0 * 24 + d1;
    #pragma unroll
    for (int t = 0; t < 9; ++t) {
        #pragma unroll
        for (int nt = 0; nt < 4; ++nt) {
            __syncthreads();
            *(f32x4*)&tbw[n * 20 + q * 4] = acc[t][nt];   // tb[o=n][m=q*4+r]
            __syncthreads();
            f32x4 v = *(const f32x4*)&tbw[o4 * 20 + mc * 4];
            const int o = nt * 16 + o4;
            v += bias[o];
            size_t off = ((size_t)(b * 64 + o) * 576 + plane) * 576
                       + (size_t)((wv * 9 + t) * 16 + mc * 4);
            *(f32x4*)(out + off) = v;
        }
    }
}

extern "C" void kernel_launch(void* const* d_in, const int* in_sizes, int n_in,
                              void* d_out, int out_size, void* d_ws, size_t ws_size,
                              hipStream_t stream) {
    const float* x    = (const float*)d_in[0];
    const float* w    = (const float*)d_in[1];
    const float* bias = (const float*)d_in[2];
    float* out        = (float*)d_out;
    unsigned short* w2 = (unsigned short*)d_ws;   // hi plane + lo plane = 663,552 B

    hipLaunchKernelGGL(wconv_kernel, dim3(648), dim3(256), 0, stream, w, w2);
    hipLaunchKernelGGL(conv4d_kernel, dim3(2 * 24 * 24), dim3(256), 0, stream,
                       x, w2, bias, out);
}

// Round 4
// 770.806 us; speedup vs baseline: 1.6340x; 1.6340x over previous
//
#include <hip/hip_runtime.h>

typedef __attribute__((ext_vector_type(8))) unsigned short us8;
typedef __attribute__((ext_vector_type(8))) __bf16 bf16x8;
typedef __attribute__((ext_vector_type(4))) float f32x4;

#define RS   1048   // LDS d2-row stride in shorts (26*40 + 8 pad -> write banks spread)
#define D3S  40     // LDS d3 stride in shorts (32 c + 8 pad; 80B rows, read-conflict-free)
#define XSZ  27232  // shorts; max read idx 25*RS + 25*D3S + 24 + 7 = 27231
#define WELEMS 165888   // 3*64*32*27 weight elements (one bf16 plane)

// Reference semantics (derived, certified by prior session):
//   out[b,o,d0,d1,d2,d3] = bias[o] + sum_{i<3, c<32, k1,k2,k3}
//       X(b, r=(d0+i)*32+c ; d1+k1-1, d2+k2-1, d3+k3-1) * w[i,o,c,k1,k2,k3]
//   where X reads x[b, ci=r/26, pf=r%26-1, ...], zero if pf or spatial idx out of [0,24).
//
// Numerics: 2-term split. x staged as single round-nearest bf16;
// w kept as bf16 hi+lo (exact to 2^-18 rel). acc += Ah*Bh + Ah*Bl.
// Dropped term = sum x_lo*w: sigma ~1.2e-3, absmax ~6e-3 << tolerance.
//
// Round-4 fix: XCD swizzle chunk was 288 (for a 2304 grid) but grid is 1152 ->
// b ran to 3 (B=2) -> OOB fault. Correct bijective chunk = 1152/8 = 144.

__device__ __forceinline__ unsigned short f2bf(float f) {
    unsigned int u = __builtin_bit_cast(unsigned int, f);
    u += 0x7FFFu + ((u >> 16) & 1u);
    return (unsigned short)(u >> 16);
}

__device__ __forceinline__ void f2bf2(float f, unsigned short& h, unsigned short& l) {
    h = f2bf(f);
    float hf = __builtin_bit_cast(float, (unsigned int)h << 16);
    l = f2bf(f - hf);
}

// w: (3,64,32,3,3,3) fp32  ->  w2 bf16 [i][k1][k2][k3][o][c], hi plane + lo plane
__global__ void wconv_kernel(const float* __restrict__ w, unsigned short* __restrict__ w2) {
    int e   = blockIdx.x * 256 + threadIdx.x;   // 648*256 = 165888 exact
    int ci  = e & 31;
    int o   = (e >> 5) & 63;
    int tap = e >> 11;
    int k3 = tap % 3;
    int k2 = (tap / 3) % 3;
    int k1 = (tap / 9) % 3;
    int i  = tap / 27;
    int src = ((i * 64 + o) * 32 + ci) * 27 + (k1 * 9 + k2 * 3 + k3);
    unsigned short h, l;
    f2bf2(w[src], h, l);
    w2[e]          = h;
    w2[e + WELEMS] = l;
}

__global__ __launch_bounds__(256, 2)
void conv4d_kernel(const float* __restrict__ x, const unsigned short* __restrict__ w2,
                   const float* __restrict__ bias, float* __restrict__ out) {
    __shared__ __align__(16) unsigned short xsh[XSZ];   // 54,464 B
    __shared__ __align__(16) float tb[4][320];          //  5,120 B  -> 2 blocks/CU

    const int tid  = threadIdx.x;
    const int lane = tid & 63;
    const int wv   = tid >> 6;
    const int n    = lane & 15;
    const int q    = lane >> 4;

    int bid = blockIdx.x;
    bid = (bid & 7) * 144 + (bid >> 3);      // XCD-aware swizzle (1152 = 8*144, bijective)
    const int d1 = bid % 24;
    const int d0 = (bid / 24) % 24;
    const int b  = bid / 576;

    for (int e = tid * 8; e < XSZ; e += 2048) *(us8*)&xsh[e] = (us8)0;

    int abase[9];
    #pragma unroll
    for (int t = 0; t < 9; ++t) {
        int mflat = (wv * 9 + t) * 16 + n;
        int d2o = mflat / 24;
        int d3o = mflat - d2o * 24;
        abase[t] = d2o * RS + d3o * D3S + q * 8;
    }

    f32x4 acc[9][4];
    #pragma unroll
    for (int t = 0; t < 9; ++t)
        #pragma unroll
        for (int nt = 0; nt < 4; ++nt)
            acc[t][nt] = (f32x4)0.0f;

    const float* xb_b = x + (size_t)b * 10616832;
    const int cbase = wv * 8;

    for (int i = 0; i < 3; ++i) {                 // f = d0+i always valid (no skip)
        const int rbase = (d0 + i) * 32;
        for (int k1 = 0; k1 < 3; ++k1) {
            int d1in = d1 + k1 - 1;
            if (d1in < 0 || d1in >= 24) continue; // spatial pad, block-uniform

            __syncthreads();
            {
                // wave wv stages c-slots cbase..cbase+7 for all 576 positions
                int   off8[8];
                float msk8[8];
                #pragma unroll
                for (int cc = 0; cc < 8; ++cc) {
                    int r  = rbase + cbase + cc;
                    int ci = r / 26;
                    int pf = r - ci * 26 - 1;       // source frame, may be pad
                    bool valid = ((unsigned)pf < 24u);
                    off8[cc] = valid ? (ci * 331776 + pf * 13824 + d1in * 576) : 0;
                    msk8[cc] = valid ? 1.0f : 0.0f;
                }
                for (int f4 = lane; f4 < 144; f4 += 64) {
                    int d2  = f4 / 6;
                    int d3c = f4 - d2 * 6;
                    int pos = d2 * 24 + d3c * 4;
                    f32x4 v[8];
                    #pragma unroll
                    for (int cc = 0; cc < 8; ++cc)
                        v[cc] = *(const f32x4*)(xb_b + off8[cc] + pos);
                    const int le = (d2 + 1) * RS + (d3c * 4 + 1) * D3S + cbase;
                    #pragma unroll
                    for (int k = 0; k < 4; ++k) {   // in-register transpose: 4 pos x 8 c
                        us8 hv;
                        #pragma unroll
                        for (int cc = 0; cc < 8; ++cc)
                            hv[cc] = f2bf(v[cc][k] * msk8[cc]);
                        *(us8*)&xsh[le + k * D3S] = hv;   // 16B, c-contiguous
                    }
                }
            }
            __syncthreads();

            const unsigned short* wsliceH = w2 + (size_t)((i * 3 + k1) * 9) * 2048;
            const unsigned short* wsliceL = wsliceH + WELEMS;
            #pragma unroll
            for (int k2 = 0; k2 < 3; ++k2) {
                #pragma unroll
                for (int k3 = 0; k3 < 3; ++k3) {
                    const int tap = k2 * 3 + k3;
                    bf16x8 bh[4], bl[4];
                    #pragma unroll
                    for (int nt = 0; nt < 4; ++nt) {
                        const int wo = (tap * 64 + nt * 16 + n) * 32 + q * 8;
                        bh[nt] = __builtin_bit_cast(bf16x8, *(const us8*)(wsliceH + wo));
                        bl[nt] = __builtin_bit_cast(bf16x8, *(const us8*)(wsliceL + wo));
                    }
                    const int toff = k2 * RS + k3 * D3S;
                    #pragma unroll
                    for (int t = 0; t < 9; ++t) {
                        const bf16x8 ah = __builtin_bit_cast(bf16x8, *(const us8*)(&xsh[abase[t] + toff]));
                        #pragma unroll
                        for (int nt = 0; nt < 4; ++nt) {
                            acc[t][nt] = __builtin_amdgcn_mfma_f32_16x16x32_bf16(ah, bh[nt], acc[t][nt], 0, 0, 0);
                            acc[t][nt] = __builtin_amdgcn_mfma_f32_16x16x32_bf16(ah, bl[nt], acc[t][nt], 0, 0, 0);
                        }
                    }
                }
            }
        }
    }

    // epilogue, interp A (col=o, row=m — certified by prior on-device probes)
    const int o4 = lane >> 2;
    const int mc = lane & 3;
    float* tbw = tb[wv];
    const size_t plane = (size_t)d0 * 24 + d1;
    #pragma unroll
    for (int t = 0; t < 9; ++t) {
        #pragma unroll
        for (int nt = 0; nt < 4; ++nt) {
            __syncthreads();
            *(f32x4*)&tbw[n * 20 + q * 4] = acc[t][nt];   // tb[o=n][m=q*4+r]
            __syncthreads();
            f32x4 v = *(const f32x4*)&tbw[o4 * 20 + mc * 4];
            const int o = nt * 16 + o4;
            v += bias[o];
            size_t off = ((size_t)(b * 64 + o) * 576 + plane) * 576
                       + (size_t)((wv * 9 + t) * 16 + mc * 4);
            *(f32x4*)(out + off) = v;
        }
    }
}

extern "C" void kernel_launch(void* const* d_in, const int* in_sizes, int n_in,
                              void* d_out, int out_size, void* d_ws, size_t ws_size,
                              hipStream_t stream) {
    const float* x    = (const float*)d_in[0];
    const float* w    = (const float*)d_in[1];
    const float* bias = (const float*)d_in[2];
    float* out        = (float*)d_out;
    unsigned short* w2 = (unsigned short*)d_ws;   // hi + lo plane = 663,552 B

    hipLaunchKernelGGL(wconv_kernel, dim3(648), dim3(256), 0, stream, w, w2);
    hipLaunchKernelGGL(conv4d_kernel, dim3(2 * 24 * 24), dim3(256), 0, stream,
                       x, w2, bias, out);
}

// Round 5
// 647.468 us; speedup vs baseline: 1.9452x; 1.1905x over previous
//
#include <hip/hip_runtime.h>

typedef __attribute__((ext_vector_type(8))) unsigned short us8;
typedef __attribute__((ext_vector_type(8))) __bf16 bf16x8;
typedef __attribute__((ext_vector_type(4))) float f32x4;

#define RS   1048   // LDS d2-row stride in shorts (26*40 + 8 pad -> write banks spread)
#define D3S  40     // LDS d3 stride in shorts (32 c + 8 pad; 80B rows, read-conflict-free)
#define XSZ  27232  // shorts; max read idx 25*RS + 25*D3S + 24 + 7 = 27231
#define WELEMS 165888   // 3*64*32*27 weight elements (one bf16 plane)

// Reference semantics (derived, certified by prior session):
//   out[b,o,d0,d1,d2,d3] = bias[o] + sum_{i<3, c<32, k1,k2,k3}
//       X(b, r=(d0+i)*32+c ; d1+k1-1, d2+k2-1, d3+k3-1) * w[i,o,c,k1,k2,k3]
//   where X reads x[b, ci=r/26, pf=r%26-1, ...], zero if pf or spatial idx out of [0,24).
//
// Numerics: 2-term split. x staged as single round-nearest bf16;
// w kept as bf16 hi+lo. acc += Ah*Bh + Ah*Bl. absmax ~6e-3 << tolerance.
//
// Round-5: explicit 2-phase pipeline. Stage s+1's global loads issue BEFORE the
// raw s_barrier (no vmcnt drain -> loads fly across barrier + MFMA phase).
// __syncthreads would drain vmcnt(0) and kill the overlap, so all barriers are
// raw s_barrier + explicit lgkmcnt(0). Epilogue tb is per-wave -> barrier-free,
// and output stores are non-temporal (the 268MB write stream was thrashing x
// out of L3: FETCH_SIZE 515MB vs 85MB input).

__device__ __forceinline__ unsigned short f2bf(float f) {
    unsigned int u = __builtin_bit_cast(unsigned int, f);
    u += 0x7FFFu + ((u >> 16) & 1u);
    return (unsigned short)(u >> 16);
}

__device__ __forceinline__ void f2bf2(float f, unsigned short& h, unsigned short& l) {
    h = f2bf(f);
    float hf = __builtin_bit_cast(float, (unsigned int)h << 16);
    l = f2bf(f - hf);
}

// w: (3,64,32,3,3,3) fp32  ->  w2 bf16 [i][k1][k2][k3][o][c], hi plane + lo plane
__global__ void wconv_kernel(const float* __restrict__ w, unsigned short* __restrict__ w2) {
    int e   = blockIdx.x * 256 + threadIdx.x;   // 648*256 = 165888 exact
    int ci  = e & 31;
    int o   = (e >> 5) & 63;
    int tap = e >> 11;
    int k3 = tap % 3;
    int k2 = (tap / 3) % 3;
    int k1 = (tap / 9) % 3;
    int i  = tap / 27;
    int src = ((i * 64 + o) * 32 + ci) * 27 + (k1 * 9 + k2 * 3 + k3);
    unsigned short h, l;
    f2bf2(w[src], h, l);
    w2[e]          = h;
    w2[e + WELEMS] = l;
}

__global__ __launch_bounds__(256, 1)
void conv4d_kernel(const float* __restrict__ x, const unsigned short* __restrict__ w2,
                   const float* __restrict__ bias, float* __restrict__ out) {
    __shared__ __align__(16) unsigned short xsh[XSZ];   // 54,464 B
    __shared__ __align__(16) float tb[4][320];          //  5,120 B (per-wave slices)

    const int tid  = threadIdx.x;
    const int lane = tid & 63;
    const int wv   = tid >> 6;
    const int n    = lane & 15;
    const int q    = lane >> 4;

    int bid = blockIdx.x;
    bid = (bid & 7) * 144 + (bid >> 3);      // XCD-aware swizzle (1152 = 8*144, bijective)
    const int d1 = bid % 24;
    const int d0 = (bid / 24) % 24;
    const int b  = bid / 576;

    for (int e = tid * 8; e < XSZ; e += 2048) *(us8*)&xsh[e] = (us8)0;

    int abase[9];
    #pragma unroll
    for (int t = 0; t < 9; ++t) {
        int mflat = (wv * 9 + t) * 16 + n;
        int d2o = mflat / 24;
        int d3o = mflat - d2o * 24;
        abase[t] = d2o * RS + d3o * D3S + q * 8;
    }

    f32x4 acc[9][4];
    #pragma unroll
    for (int t = 0; t < 9; ++t)
        #pragma unroll
        for (int nt = 0; nt < 4; ++nt)
            acc[t][nt] = (f32x4)0.0f;

    const float* xb_b = x + (size_t)b * 10616832;
    const int cbase = wv * 8;

    // stage enumeration: s -> (i = s/nk, k1 = k1lo + s%nk); block-uniform
    const int k1lo = (d1 == 0) ? 1 : 0;
    const int k1hi = (d1 == 23) ? 1 : 2;
    const int nk = k1hi - k1lo + 1;
    const int ns = 3 * nk;

    f32x4 v[3][8];          // prefetch buffer: 18 float4/lane (jj=2 only lanes<16)
    float mskC[8], mskN[8];

    // prologue: issue loads for stage 0
    {
        const int d1in = d1 + k1lo - 1;
        int off0[8];
        #pragma unroll
        for (int cc = 0; cc < 8; ++cc) {
            int r  = d0 * 32 + cbase + cc;
            int ci = r / 26;
            int pf = r - ci * 26 - 1;
            bool valid = ((unsigned)pf < 24u);
            off0[cc] = valid ? (ci * 331776 + pf * 13824 + d1in * 576) : 0;
            mskC[cc] = valid ? 1.0f : 0.0f;
        }
        #pragma unroll
        for (int jj = 0; jj < 3; ++jj) {
            int f4 = lane + 64 * jj;
            if (f4 < 144) {
                int d2  = f4 / 6;
                int d3c = f4 - d2 * 6;
                int pos = d2 * 24 + d3c * 4;
                #pragma unroll
                for (int cc = 0; cc < 8; ++cc)
                    v[jj][cc] = *(const f32x4*)(xb_b + off0[cc] + pos);
            }
        }
    }

    for (int s = 0; s < ns; ++s) {
        // phase 1: convert + ds_write stage s (data already in v)
        #pragma unroll
        for (int jj = 0; jj < 3; ++jj) {
            int f4 = lane + 64 * jj;
            if (f4 < 144) {
                int d2  = f4 / 6;
                int d3c = f4 - d2 * 6;
                const int le = (d2 + 1) * RS + (d3c * 4 + 1) * D3S + cbase;
                #pragma unroll
                for (int k = 0; k < 4; ++k) {
                    us8 hv;
                    #pragma unroll
                    for (int cc = 0; cc < 8; ++cc)
                        hv[cc] = f2bf(v[jj][cc][k] * mskC[cc]);
                    *(us8*)&xsh[le + k * D3S] = hv;
                }
            }
        }

        // phase 2: issue stage s+1 loads (fly across the raw barrier + MFMA phase)
        if (s + 1 < ns) {
            const int sn   = s + 1;
            const int i_n  = sn / nk;
            const int k1_n = k1lo + (sn - i_n * nk);
            const int d1in = d1 + k1_n - 1;
            int offn[8];
            #pragma unroll
            for (int cc = 0; cc < 8; ++cc) {
                int r  = (d0 + i_n) * 32 + cbase + cc;
                int ci = r / 26;
                int pf = r - ci * 26 - 1;
                bool valid = ((unsigned)pf < 24u);
                offn[cc] = valid ? (ci * 331776 + pf * 13824 + d1in * 576) : 0;
                mskN[cc] = valid ? 1.0f : 0.0f;
            }
            #pragma unroll
            for (int jj = 0; jj < 3; ++jj) {
                int f4 = lane + 64 * jj;
                if (f4 < 144) {
                    int d2  = f4 / 6;
                    int d3c = f4 - d2 * 6;
                    int pos = d2 * 24 + d3c * 4;
                    #pragma unroll
                    for (int cc = 0; cc < 8; ++cc)
                        v[jj][cc] = *(const f32x4*)(xb_b + offn[cc] + pos);
                }
            }
            #pragma unroll
            for (int cc = 0; cc < 8; ++cc) mskC[cc] = mskN[cc];
        }

        // raw barrier: LDS writes visible; prefetch loads NOT drained
        asm volatile("s_waitcnt lgkmcnt(0)" ::: "memory");
        __builtin_amdgcn_s_barrier();
        asm volatile("" ::: "memory");

        // phase 3: MFMA for stage s
        const int ik  = s / nk;
        const int k1c = k1lo + (s - ik * nk);
        const unsigned short* wsliceH = w2 + (size_t)((ik * 3 + k1c) * 9) * 2048;
        const unsigned short* wsliceL = wsliceH + WELEMS;
        __builtin_amdgcn_s_setprio(1);
        #pragma unroll
        for (int k2 = 0; k2 < 3; ++k2) {
            #pragma unroll
            for (int k3 = 0; k3 < 3; ++k3) {
                const int tap = k2 * 3 + k3;
                bf16x8 bh[4], bl[4];
                #pragma unroll
                for (int nt = 0; nt < 4; ++nt) {
                    const int wo = (tap * 64 + nt * 16 + n) * 32 + q * 8;
                    bh[nt] = __builtin_bit_cast(bf16x8, *(const us8*)(wsliceH + wo));
                    bl[nt] = __builtin_bit_cast(bf16x8, *(const us8*)(wsliceL + wo));
                }
                const int toff = k2 * RS + k3 * D3S;
                #pragma unroll
                for (int t = 0; t < 9; ++t) {
                    const bf16x8 ah = __builtin_bit_cast(bf16x8, *(const us8*)(&xsh[abase[t] + toff]));
                    #pragma unroll
                    for (int nt = 0; nt < 4; ++nt) {
                        acc[t][nt] = __builtin_amdgcn_mfma_f32_16x16x32_bf16(ah, bh[nt], acc[t][nt], 0, 0, 0);
                        acc[t][nt] = __builtin_amdgcn_mfma_f32_16x16x32_bf16(ah, bl[nt], acc[t][nt], 0, 0, 0);
                    }
                }
            }
        }
        __builtin_amdgcn_s_setprio(0);

        // raw barrier: all waves done reading xsh before next stage overwrites
        asm volatile("" ::: "memory");
        __builtin_amdgcn_s_barrier();
        asm volatile("" ::: "memory");
    }

    // epilogue, interp A (col=o, row=m — certified by prior on-device probes).
    // tb[wv] is PER-WAVE: in-wave LDS RAW needs only lgkmcnt(0), no barriers.
    const int o4 = lane >> 2;
    const int mc = lane & 3;
    float* tbw = tb[wv];
    const size_t plane = (size_t)d0 * 24 + d1;
    #pragma unroll
    for (int t = 0; t < 9; ++t) {
        #pragma unroll
        for (int nt = 0; nt < 4; ++nt) {
            asm volatile("" ::: "memory");
            *(f32x4*)&tbw[n * 20 + q * 4] = acc[t][nt];   // tb[o=n][m=q*4+r]
            asm volatile("s_waitcnt lgkmcnt(0)" ::: "memory");
            f32x4 vv = *(const f32x4*)&tbw[o4 * 20 + mc * 4];
            const int o = nt * 16 + o4;
            vv += bias[o];
            size_t off = ((size_t)(b * 64 + o) * 576 + plane) * 576
                       + (size_t)((wv * 9 + t) * 16 + mc * 4);
            __builtin_nontemporal_store(vv, (f32x4*)(out + off));
        }
    }
}

extern "C" void kernel_launch(void* const* d_in, const int* in_sizes, int n_in,
                              void* d_out, int out_size, void* d_ws, size_t ws_size,
                              hipStream_t stream) {
    const float* x    = (const float*)d_in[0];
    const float* w    = (const float*)d_in[1];
    const float* bias = (const float*)d_in[2];
    float* out        = (float*)d_out;
    unsigned short* w2 = (unsigned short*)d_ws;   // hi + lo plane = 663,552 B

    hipLaunchKernelGGL(wconv_kernel, dim3(648), dim3(256), 0, stream, w, w2);
    hipLaunchKernelGGL(conv4d_kernel, dim3(2 * 24 * 24), dim3(256), 0, stream,
                       x, w2, bias, out);
}

// Round 6
// 625.217 us; speedup vs baseline: 2.0144x; 1.0356x over previous
//
#include <hip/hip_runtime.h>

typedef __attribute__((ext_vector_type(8))) unsigned short us8;
typedef __attribute__((ext_vector_type(8))) __bf16 bf16x8;
typedef __attribute__((ext_vector_type(4))) float f32x4;

#define RS   1048   // LDS d2-row stride in shorts (26*40 + 8 pad)
#define D3S  40     // LDS d3 stride in shorts (32 c + 8 pad; 80B rows, read-conflict-free)
#define XSZ  27232  // shorts; max read idx 25*RS + 25*D3S + 24 + 7 = 27231
#define WELEMS 165888   // 3*64*32*27 weight elements (one bf16 plane)
#define WSLICE 18432    // shorts per (i,k1) weight slice per plane (9 taps * 64 o * 32 c)

// Reference semantics (derived, certified by prior session):
//   out[b,o,d0,d1,d2,d3] = bias[o] + sum_{i<3, c<32, k1,k2,k3}
//       X(b, r=(d0+i)*32+c ; d1+k1-1, d2+k2-1, d3+k3-1) * w[i,o,c,k1,k2,k3]
//   where X reads x[b, ci=r/26, pf=r%26-1, ...], zero if pf or spatial idx out of [0,24).
//
// Numerics: 2-term split. x staged as single round-nearest bf16;
// w kept as bf16 hi+lo. acc += Ah*Bh + Ah*Bl. absmax ~6e-3 << tolerance.
//
// Round-6: weight slice staged into LDS via global_load_lds (DMA, no VGPRs, linear
// copy -> fragment read formula unchanged, just LDS base). Removes 144 per-wave
// L2 fragment loads per stage (295KB/CU/stage -> 73.7KB) and their tap-serialized
// latency. Counted vmcnt(24) before the barrier waits the 18 w-DMAs while the 24
// x-prefetch loads stay in flight across barrier + MFMA (round-5 pipeline kept).

__device__ __forceinline__ unsigned short f2bf(float f) {
    unsigned int u = __builtin_bit_cast(unsigned int, f);
    u += 0x7FFFu + ((u >> 16) & 1u);
    return (unsigned short)(u >> 16);
}

__device__ __forceinline__ void f2bf2(float f, unsigned short& h, unsigned short& l) {
    h = f2bf(f);
    float hf = __builtin_bit_cast(float, (unsigned int)h << 16);
    l = f2bf(f - hf);
}

// w: (3,64,32,3,3,3) fp32  ->  w2 bf16 [i][k1][k2][k3][o][c], hi plane + lo plane
__global__ void wconv_kernel(const float* __restrict__ w, unsigned short* __restrict__ w2) {
    int e   = blockIdx.x * 256 + threadIdx.x;   // 648*256 = 165888 exact
    int ci  = e & 31;
    int o   = (e >> 5) & 63;
    int tap = e >> 11;
    int k3 = tap % 3;
    int k2 = (tap / 3) % 3;
    int k1 = (tap / 9) % 3;
    int i  = tap / 27;
    int src = ((i * 64 + o) * 32 + ci) * 27 + (k1 * 9 + k2 * 3 + k3);
    unsigned short h, l;
    f2bf2(w[src], h, l);
    w2[e]          = h;
    w2[e + WELEMS] = l;
}

typedef __attribute__((address_space(1))) const unsigned short gus_t;
typedef __attribute__((address_space(3))) unsigned short lus_t;

__global__ __launch_bounds__(256, 1)
void conv4d_kernel(const float* __restrict__ x, const unsigned short* __restrict__ w2,
                   const float* __restrict__ bias, float* __restrict__ out) {
    __shared__ __align__(16) unsigned short xsh[XSZ];        // 54,464 B
    __shared__ __align__(16) unsigned short wsh[2 * WSLICE]; // 73,728 B (hi | lo)
    __shared__ __align__(16) float tb[4][320];               //  5,120 B (per-wave)

    const int tid  = threadIdx.x;
    const int lane = tid & 63;
    const int wv   = tid >> 6;
    const int n    = lane & 15;
    const int q    = lane >> 4;

    int bid = blockIdx.x;
    bid = (bid & 7) * 144 + (bid >> 3);      // XCD-aware swizzle (1152 = 8*144, bijective)
    const int d1 = bid % 24;
    const int d0 = (bid / 24) % 24;
    const int b  = bid / 576;

    for (int e = tid * 8; e < XSZ; e += 2048) *(us8*)&xsh[e] = (us8)0;

    int abase[9];
    #pragma unroll
    for (int t = 0; t < 9; ++t) {
        int mflat = (wv * 9 + t) * 16 + n;
        int d2o = mflat / 24;
        int d3o = mflat - d2o * 24;
        abase[t] = d2o * RS + d3o * D3S + q * 8;
    }

    f32x4 acc[9][4];
    #pragma unroll
    for (int t = 0; t < 9; ++t)
        #pragma unroll
        for (int nt = 0; nt < 4; ++nt)
            acc[t][nt] = (f32x4)0.0f;

    const float* xb_b = x + (size_t)b * 10616832;
    const int cbase = wv * 8;

    // stage enumeration: s -> (i = s/nk, k1 = k1lo + s%nk); block-uniform
    const int k1lo = (d1 == 0) ? 1 : 0;
    const int k1hi = (d1 == 23) ? 1 : 2;
    const int nk = k1hi - k1lo + 1;
    const int ns = 3 * nk;

    f32x4 v[3][8];          // prefetch buffer (jj=2 only lanes<16): 24 load insts/wave
    float mskC[8], mskN[8];

    // prologue: issue loads for stage 0
    {
        const int d1in = d1 + k1lo - 1;
        int off0[8];
        #pragma unroll
        for (int cc = 0; cc < 8; ++cc) {
            int r  = d0 * 32 + cbase + cc;
            int ci = r / 26;
            int pf = r - ci * 26 - 1;
            bool valid = ((unsigned)pf < 24u);
            off0[cc] = valid ? (ci * 331776 + pf * 13824 + d1in * 576) : 0;
            mskC[cc] = valid ? 1.0f : 0.0f;
        }
        #pragma unroll
        for (int jj = 0; jj < 3; ++jj) {
            int f4 = lane + 64 * jj;
            if (f4 < 144) {
                int d2  = f4 / 6;
                int d3c = f4 - d2 * 6;
                int pos = d2 * 24 + d3c * 4;
                #pragma unroll
                for (int cc = 0; cc < 8; ++cc)
                    v[jj][cc] = *(const f32x4*)(xb_b + off0[cc] + pos);
            }
        }
    }

    for (int s = 0; s < ns; ++s) {
        const int ik  = s / nk;
        const int k1c = k1lo + (s - ik * nk);

        // (a) issue weight-slice DMA for THIS stage: 9 hi + 9 lo insts/wave,
        //     1KB each, linear copy. LDS dst base wave-uniform; HW adds lane*16B.
        {
            const unsigned short* wgH = w2 + (size_t)((ik * 3 + k1c) * 9) * 2048;
            #pragma unroll
            for (int j = 0; j < 9; ++j) {
                const int blk = (wv * 9 + j) * 512;   // shorts
                __builtin_amdgcn_global_load_lds((gus_t*)(wgH + blk + lane * 8),
                                                 (lus_t*)&wsh[blk], 16, 0, 0);
            }
            #pragma unroll
            for (int j = 0; j < 9; ++j) {
                const int blk = (wv * 9 + j) * 512;
                __builtin_amdgcn_global_load_lds((gus_t*)(wgH + WELEMS + blk + lane * 8),
                                                 (lus_t*)&wsh[WSLICE + blk], 16, 0, 0);
            }
        }
        __builtin_amdgcn_sched_barrier(0);

        // (b) phase 1: convert + ds_write stage s (data already in v)
        #pragma unroll
        for (int jj = 0; jj < 3; ++jj) {
            int f4 = lane + 64 * jj;
            if (f4 < 144) {
                int d2  = f4 / 6;
                int d3c = f4 - d2 * 6;
                const int le = (d2 + 1) * RS + (d3c * 4 + 1) * D3S + cbase;
                #pragma unroll
                for (int k = 0; k < 4; ++k) {
                    us8 hv;
                    #pragma unroll
                    for (int cc = 0; cc < 8; ++cc)
                        hv[cc] = f2bf(v[jj][cc][k] * mskC[cc]);
                    *(us8*)&xsh[le + k * D3S] = hv;
                }
            }
        }

        // (c) phase 2: issue stage s+1 x loads (fly across barrier + MFMA phase)
        if (s + 1 < ns) {
            const int sn   = s + 1;
            const int i_n  = sn / nk;
            const int k1_n = k1lo + (sn - i_n * nk);
            const int d1in = d1 + k1_n - 1;
            int offn[8];
            #pragma unroll
            for (int cc = 0; cc < 8; ++cc) {
                int r  = (d0 + i_n) * 32 + cbase + cc;
                int ci = r / 26;
                int pf = r - ci * 26 - 1;
                bool valid = ((unsigned)pf < 24u);
                offn[cc] = valid ? (ci * 331776 + pf * 13824 + d1in * 576) : 0;
                mskN[cc] = valid ? 1.0f : 0.0f;
            }
            #pragma unroll
            for (int jj = 0; jj < 3; ++jj) {
                int f4 = lane + 64 * jj;
                if (f4 < 144) {
                    int d2  = f4 / 6;
                    int d3c = f4 - d2 * 6;
                    int pos = d2 * 24 + d3c * 4;
                    #pragma unroll
                    for (int cc = 0; cc < 8; ++cc)
                        v[jj][cc] = *(const f32x4*)(xb_b + offn[cc] + pos);
                }
            }
            #pragma unroll
            for (int cc = 0; cc < 8; ++cc) mskC[cc] = mskN[cc];
        }
        __builtin_amdgcn_sched_barrier(0);

        // (d) wait weight DMA (18 insts) done, leave the 24 newest x loads flying
        if (s + 1 < ns) asm volatile("s_waitcnt vmcnt(24)" ::: "memory");
        else            asm volatile("s_waitcnt vmcnt(0)"  ::: "memory");
        asm volatile("s_waitcnt lgkmcnt(0)" ::: "memory");
        __builtin_amdgcn_s_barrier();
        asm volatile("" ::: "memory");

        // (e) MFMA for stage s; weights now read from LDS (conflict-free: (4n+q)%8 uniform)
        __builtin_amdgcn_s_setprio(1);
        #pragma unroll
        for (int k2 = 0; k2 < 3; ++k2) {
            #pragma unroll
            for (int k3 = 0; k3 < 3; ++k3) {
                const int tap = k2 * 3 + k3;
                bf16x8 bh[4], bl[4];
                #pragma unroll
                for (int nt = 0; nt < 4; ++nt) {
                    const int wo = (tap * 64 + nt * 16 + n) * 32 + q * 8;
                    bh[nt] = __builtin_bit_cast(bf16x8, *(const us8*)(&wsh[wo]));
                    bl[nt] = __builtin_bit_cast(bf16x8, *(const us8*)(&wsh[WSLICE + wo]));
                }
                const int toff = k2 * RS + k3 * D3S;
                #pragma unroll
                for (int t = 0; t < 9; ++t) {
                    const bf16x8 ah = __builtin_bit_cast(bf16x8, *(const us8*)(&xsh[abase[t] + toff]));
                    #pragma unroll
                    for (int nt = 0; nt < 4; ++nt) {
                        acc[t][nt] = __builtin_amdgcn_mfma_f32_16x16x32_bf16(ah, bh[nt], acc[t][nt], 0, 0, 0);
                        acc[t][nt] = __builtin_amdgcn_mfma_f32_16x16x32_bf16(ah, bl[nt], acc[t][nt], 0, 0, 0);
                    }
                }
            }
        }
        __builtin_amdgcn_s_setprio(0);

        // all waves done reading xsh/wsh before next stage overwrites
        asm volatile("" ::: "memory");
        __builtin_amdgcn_s_barrier();
        asm volatile("" ::: "memory");
    }

    // epilogue, interp A (col=o, row=m — certified by prior on-device probes).
    // tb[wv] is PER-WAVE: in-wave LDS RAW needs only lgkmcnt(0), no barriers.
    const int o4 = lane >> 2;
    const int mc = lane & 3;
    float* tbw = tb[wv];
    const size_t plane = (size_t)d0 * 24 + d1;
    #pragma unroll
    for (int t = 0; t < 9; ++t) {
        #pragma unroll
        for (int nt = 0; nt < 4; ++nt) {
            asm volatile("" ::: "memory");
            *(f32x4*)&tbw[n * 20 + q * 4] = acc[t][nt];   // tb[o=n][m=q*4+r]
            asm volatile("s_waitcnt lgkmcnt(0)" ::: "memory");
            f32x4 vv = *(const f32x4*)&tbw[o4 * 20 + mc * 4];
            const int o = nt * 16 + o4;
            vv += bias[o];
            size_t off = ((size_t)(b * 64 + o) * 576 + plane) * 576
                       + (size_t)((wv * 9 + t) * 16 + mc * 4);
            __builtin_nontemporal_store(vv, (f32x4*)(out + off));
        }
    }
}

extern "C" void kernel_launch(void* const* d_in, const int* in_sizes, int n_in,
                              void* d_out, int out_size, void* d_ws, size_t ws_size,
                              hipStream_t stream) {
    const float* x    = (const float*)d_in[0];
    const float* w    = (const float*)d_in[1];
    const float* bias = (const float*)d_in[2];
    float* out        = (float*)d_out;
    unsigned short* w2 = (unsigned short*)d_ws;   // hi + lo plane = 663,552 B

    hipLaunchKernelGGL(wconv_kernel, dim3(648), dim3(256), 0, stream, w, w2);
    hipLaunchKernelGGL(conv4d_kernel, dim3(2 * 24 * 24), dim3(256), 0, stream,
                       x, w2, bias, out);
}